// Round 5
// baseline (1727.469 us; speedup 1.0000x reference)
//
#include <hip/hip_runtime.h>
#include <hip/hip_bf16.h>
#include <math.h>

#define N_NODES 50000
#define N_EDGES 500000
#define H 128
#define NL 3
#define SCAN_B 256
#define NCHUNK ((N_NODES + SCAN_B - 1) / SCAN_B)

typedef short short8v __attribute__((ext_vector_type(8)));
typedef float f32x4 __attribute__((ext_vector_type(4)));
typedef unsigned short ushort8v __attribute__((ext_vector_type(8)));
typedef unsigned short ushort4v __attribute__((ext_vector_type(4)));

__device__ __forceinline__ unsigned short f2b(float f) {
  __hip_bfloat16 h = __float2bfloat16(f);
  return __builtin_bit_cast(unsigned short, h);
}
__device__ __forceinline__ float b2f(unsigned short s) {
  unsigned u = (unsigned)s << 16;
  return __builtin_bit_cast(float, u);
}
__device__ __forceinline__ short8v pack8(float4 a, float4 b) {
  ushort8v v;
  v[0] = f2b(a.x); v[1] = f2b(a.y); v[2] = f2b(a.z); v[3] = f2b(a.w);
  v[4] = f2b(b.x); v[5] = f2b(b.y); v[6] = f2b(b.z); v[7] = f2b(b.w);
  return __builtin_bit_cast(short8v, v);
}

#define MFMA16(A, B, C) __builtin_amdgcn_mfma_f32_16x16x32_bf16(A, B, C, 0, 0, 0)

// ---------------- counting sort of edges by dst ----------------

__global__ void k_deg_i(const int* __restrict__ dst, int* __restrict__ degC) {
  int e = blockIdx.x * blockDim.x + threadIdx.x;
  if (e < N_EDGES) atomicAdd(&degC[dst[e]], 1);
}

__global__ void k_scan1(const int* __restrict__ degC, int* __restrict__ cursor,
                        int* __restrict__ chunkSum, float* __restrict__ invd) {
  __shared__ int s[SCAN_B];
  int t = threadIdx.x, i = blockIdx.x * SCAN_B + t;
  int v = (i < N_NODES) ? degC[i] : 0;
  s[t] = v;
  __syncthreads();
  for (int o = 1; o < SCAN_B; o <<= 1) {
    int u = (t >= o) ? s[t - o] : 0;
    __syncthreads();
    s[t] += u;
    __syncthreads();
  }
  if (i < N_NODES) {
    cursor[i] = s[t] - v;
    invd[i] = 1.0f / fmaxf((float)v, 1.0f);
  }
  if (t == SCAN_B - 1) chunkSum[blockIdx.x] = s[t];
}

__global__ void k_scan2(int* __restrict__ chunkSum) {
  __shared__ int s[SCAN_B];
  int t = threadIdx.x;
  int v = (t < NCHUNK) ? chunkSum[t] : 0;
  s[t] = v;
  __syncthreads();
  for (int o = 1; o < SCAN_B; o <<= 1) {
    int u = (t >= o) ? s[t - o] : 0;
    __syncthreads();
    s[t] += u;
    __syncthreads();
  }
  if (t < NCHUNK) chunkSum[t] = s[t] - v;
}

__global__ void k_scan3(int* __restrict__ cursor, const int* __restrict__ chunkSum) {
  int i = blockIdx.x * SCAN_B + threadIdx.x;
  if (i < N_NODES) cursor[i] += chunkSum[blockIdx.x];
}

__global__ void k_scatter_sort(const int* __restrict__ dst, int* __restrict__ cursor,
                               int* __restrict__ sorted) {
  int e = blockIdx.x * blockDim.x + threadIdx.x;
  if (e < N_EDGES) {
    int p = atomicAdd(&cursor[dst[e]], 1);
    sorted[p] = e;
  }
}

// ---------------- conversions ----------------

__global__ void k_cvt_x(const float* __restrict__ x, unsigned short* __restrict__ xb, int n4) {
  int i = blockIdx.x * blockDim.x + threadIdx.x;
  if (i < n4) {
    float4 v = ((const float4*)x)[i];
    ushort4v o;
    o[0] = f2b(v.x); o[1] = f2b(v.y); o[2] = f2b(v.z); o[3] = f2b(v.w);
    ((ushort4v*)xb)[i] = o;
  }
}

// all 5 weight tensors: [L][K][N] fp32 -> [L][N][K] bf16
__global__ void k_cvt_w(const float* __restrict__ mW1, const float* __restrict__ mW2,
                        const float* __restrict__ aW1, const float* __restrict__ nW1,
                        const float* __restrict__ nW2,
                        unsigned short* __restrict__ mW1t, unsigned short* __restrict__ mW2t,
                        unsigned short* __restrict__ aW1t, unsigned short* __restrict__ nW1t,
                        unsigned short* __restrict__ nW2t) {
  int i = blockIdx.x * blockDim.x + threadIdx.x;
  if (i < 147456) {                       // mW1 [l][384][128]
    int l = i / 49152, r = i % 49152, k = r / 128, n = r % 128;
    mW1t[((size_t)l * 128 + n) * 384 + k] = f2b(mW1[i]);
  } else if (i < 196608) {                // mW2 [l][128][128]
    int j = i - 147456;
    int l = j / 16384, r = j % 16384, k = r / 128, n = r % 128;
    mW2t[((size_t)l * 128 + n) * 128 + k] = f2b(mW2[j]);
  } else if (i < 294912) {                // aW1 [l][128][256]
    int j = i - 196608;
    int l = j / 32768, r = j % 32768, k = r / 256, n = r % 256;
    aW1t[((size_t)l * 256 + n) * 128 + k] = f2b(aW1[j]);
  } else if (i < 491520) {                // nW1 [l][256][256]
    int j = i - 294912;
    int l = j / 65536, r = j % 65536, k = r / 256, n = r % 256;
    nW1t[((size_t)l * 256 + n) * 256 + k] = f2b(nW1[j]);
  } else if (i < 589824) {                // nW2 [l][256][128]
    int j = i - 491520;
    int l = j / 32768, r = j % 32768, k = r / 128, n = r % 128;
    nW2t[((size_t)l * 128 + n) * 256 + k] = f2b(nW2[j]);
  }
}

// ---------------- fused edge kernel: col-split waves, direct-to-reg operands --
// 256 thr = 4 waves. Wave wv owns output cols [wv*32, wv*32+32). Rows: 4 row-
// tiles rt (row = rt*16 + ln15 for A; rt*16 + quad*4 + r for C/D).
// Only LDS use: sM (h1 -> m transpose) + epilogue staging. 5 barriers/block.

__launch_bounds__(256, 4)
__global__ void k_edge(const unsigned short* __restrict__ xb,
                       const float* __restrict__ pos,
                       const float* __restrict__ eattr,
                       const int* __restrict__ srcI, const int* __restrict__ dstI,
                       const int* __restrict__ sorted,
                       const unsigned short* __restrict__ mW1t, const float* __restrict__ mb1,
                       const unsigned short* __restrict__ mW2t, const float* __restrict__ mb2,
                       const unsigned short* __restrict__ aW1t, const float* __restrict__ ab1,
                       const float* __restrict__ aW2, const float* __restrict__ ab2,
                       float* __restrict__ intra, float* __restrict__ pdelta,
                       int do_intra)
{
  __shared__ unsigned short sM[64 * 136];
  __shared__ int sSrc[64], sDst[64];
  __shared__ float sWp[4][64];
  __shared__ float sPE[64 * 3];
  __shared__ int sRunS[64], sRunE[64];
  __shared__ int sNR;

  const int tid = threadIdx.x;
  const int e0 = blockIdx.x * 64;
  const int nv = min(N_EDGES - e0, 64);
  const int wv = tid >> 6, lane = tid & 63, quad = lane >> 4, ln15 = lane & 15;
  const int col = wv * 32 + ln15;  // + ct*16

  int eid_r[4], src_r[4], dst_r[4];
#pragma unroll
  for (int rt = 0; rt < 4; ++rt) {
    int idx = min(e0 + rt * 16 + ln15, N_EDGES - 1);
    int eid = sorted[idx];
    eid_r[rt] = eid; src_r[rt] = srcI[eid]; dst_r[rt] = dstI[eid];
  }
  if (tid < 64) {
    int idx = min(e0 + tid, N_EDGES - 1);
    int eid = sorted[idx];
    sSrc[tid] = srcI[eid]; sDst[tid] = dstI[eid];
  }

  f32x4 acc[4][2];
#pragma unroll
  for (int rt = 0; rt < 4; ++rt)
#pragma unroll
    for (int ct = 0; ct < 2; ++ct) acc[rt][ct] = (f32x4){0.f, 0.f, 0.f, 0.f};

  // ---- GEMM1: concat(x[dst], x[src], eattr) [64,384] @ mW1 — no LDS, no barriers
  for (int c = 0; c < 6; ++c) {
    short8v af[4][2];
    if (c < 4) {
#pragma unroll
      for (int rt = 0; rt < 4; ++rt) {
        int node = (c < 2) ? dst_r[rt] : src_r[rt];
        const unsigned short* p = xb + (size_t)node * H + (c & 1) * 64 + quad * 8;
        af[rt][0] = *(const short8v*)p;
        af[rt][1] = *(const short8v*)(p + 32);
      }
    } else {
#pragma unroll
      for (int rt = 0; rt < 4; ++rt) {
        const float* p = eattr + (size_t)eid_r[rt] * H + (c - 4) * 64 + quad * 8;
        float4 q0 = *(const float4*)p;
        float4 q1 = *(const float4*)(p + 4);
        float4 q2 = *(const float4*)(p + 32);
        float4 q3 = *(const float4*)(p + 36);
        af[rt][0] = pack8(q0, q1);
        af[rt][1] = pack8(q2, q3);
      }
    }
    short8v bf[2][2];
#pragma unroll
    for (int ct = 0; ct < 2; ++ct) {
      const unsigned short* p = mW1t + (size_t)(col + ct * 16) * 384 + c * 64 + quad * 8;
      bf[ct][0] = *(const short8v*)p;
      bf[ct][1] = *(const short8v*)(p + 32);
    }
#pragma unroll
    for (int ks = 0; ks < 2; ++ks)
#pragma unroll
      for (int rt = 0; rt < 4; ++rt)
#pragma unroll
        for (int ct = 0; ct < 2; ++ct)
          acc[rt][ct] = MFMA16(af[rt][ks], bf[ct][ks], acc[rt][ct]);
  }

  // h1 = relu(acc + mb1) -> sM
  {
    float b0 = mb1[col], b1 = mb1[col + 16];
#pragma unroll
    for (int rt = 0; rt < 4; ++rt)
#pragma unroll
      for (int r = 0; r < 4; ++r) {
        int row = rt * 16 + quad * 4 + r;
        sM[row * 136 + col] = f2b(fmaxf(acc[rt][0][r] + b0, 0.f));
        sM[row * 136 + col + 16] = f2b(fmaxf(acc[rt][1][r] + b1, 0.f));
        acc[rt][0][r] = 0.f; acc[rt][1][r] = 0.f;
      }
  }
  __syncthreads();

  // ---- GEMM2: h1 [64,128] @ mW2 (A from sM, B direct) ----
  for (int c = 0; c < 2; ++c) {
    short8v af[4][2];
#pragma unroll
    for (int rt = 0; rt < 4; ++rt) {
      const unsigned short* p = &sM[(rt * 16 + ln15) * 136 + c * 64 + quad * 8];
      af[rt][0] = *(const short8v*)p;
      af[rt][1] = *(const short8v*)(p + 32);
    }
    short8v bf[2][2];
#pragma unroll
    for (int ct = 0; ct < 2; ++ct) {
      const unsigned short* p = mW2t + (size_t)(col + ct * 16) * 128 + c * 64 + quad * 8;
      bf[ct][0] = *(const short8v*)p;
      bf[ct][1] = *(const short8v*)(p + 32);
    }
#pragma unroll
    for (int ks = 0; ks < 2; ++ks)
#pragma unroll
      for (int rt = 0; rt < 4; ++rt)
#pragma unroll
        for (int ct = 0; ct < 2; ++ct)
          acc[rt][ct] = MFMA16(af[rt][ks], bf[ct][ks], acc[rt][ct]);
  }
  __syncthreads();  // all h1 reads done

  // m = acc + mb2 -> sM
  {
    float b0 = mb2[col], b1 = mb2[col + 16];
#pragma unroll
    for (int rt = 0; rt < 4; ++rt)
#pragma unroll
      for (int r = 0; r < 4; ++r) {
        int row = rt * 16 + quad * 4 + r;
        sM[row * 136 + col] = f2b(acc[rt][0][r] + b0);
        sM[row * 136 + col + 16] = f2b(acc[rt][1][r] + b1);
      }
  }
  __syncthreads();

  // ---- acc MLP: w = relu(m @ aW1 + ab1) @ aW2 + ab2 ----
  f32x4 wsum[4];
#pragma unroll
  for (int rt = 0; rt < 4; ++rt) wsum[rt] = (f32x4){0.f, 0.f, 0.f, 0.f};

  for (int h = 0; h < 2; ++h) {
#pragma unroll
    for (int rt = 0; rt < 4; ++rt)
#pragma unroll
      for (int ct = 0; ct < 2; ++ct) acc[rt][ct] = (f32x4){0.f, 0.f, 0.f, 0.f};
    for (int c = 0; c < 2; ++c) {
      short8v af[4][2];
#pragma unroll
      for (int rt = 0; rt < 4; ++rt) {
        const unsigned short* p = &sM[(rt * 16 + ln15) * 136 + c * 64 + quad * 8];
        af[rt][0] = *(const short8v*)p;
        af[rt][1] = *(const short8v*)(p + 32);
      }
      short8v bf[2][2];
#pragma unroll
      for (int ct = 0; ct < 2; ++ct) {
        const unsigned short* p = aW1t + (size_t)(h * 128 + col + ct * 16) * 128 + c * 64 + quad * 8;
        bf[ct][0] = *(const short8v*)p;
        bf[ct][1] = *(const short8v*)(p + 32);
      }
#pragma unroll
      for (int ks = 0; ks < 2; ++ks)
#pragma unroll
        for (int rt = 0; rt < 4; ++rt)
#pragma unroll
          for (int ct = 0; ct < 2; ++ct)
            acc[rt][ct] = MFMA16(af[rt][ks], bf[ct][ks], acc[rt][ct]);
    }
    float ab0 = ab1[h * 128 + col], ab1c = ab1[h * 128 + col + 16];
    float aw0 = aW2[h * 128 + col], aw1c = aW2[h * 128 + col + 16];
#pragma unroll
    for (int rt = 0; rt < 4; ++rt)
#pragma unroll
      for (int r = 0; r < 4; ++r)
        wsum[rt][r] += fmaxf(acc[rt][0][r] + ab0, 0.f) * aw0
                     + fmaxf(acc[rt][1][r] + ab1c, 0.f) * aw1c;
  }
  // reduce over the 16 col-lanes (ln15)
#pragma unroll
  for (int m = 1; m <= 8; m <<= 1)
#pragma unroll
    for (int rt = 0; rt < 4; ++rt) {
      wsum[rt][0] += __shfl_xor(wsum[rt][0], m, 64);
      wsum[rt][1] += __shfl_xor(wsum[rt][1], m, 64);
      wsum[rt][2] += __shfl_xor(wsum[rt][2], m, 64);
      wsum[rt][3] += __shfl_xor(wsum[rt][3], m, 64);
    }
  if (ln15 == 0) {
#pragma unroll
    for (int rt = 0; rt < 4; ++rt)
#pragma unroll
      for (int r = 0; r < 4; ++r)
        sWp[wv][rt * 16 + quad * 4 + r] = wsum[rt][r];
  }
  __syncthreads();

  // ---- w -> acc_e; run detection (tid<64 is exactly wave 0) ----
  if (tid < 64) {
    float w = sWp[0][tid] + sWp[1][tid] + sWp[2][tid] + sWp[3][tid] + ab2[0];
    if (tid < nv) {
      int s = sSrc[tid], d = sDst[tid];
      float rx = pos[s * 3 + 0] - pos[d * 3 + 0];
      float ry = pos[s * 3 + 1] - pos[d * 3 + 1];
      float rz = pos[s * 3 + 2] - pos[d * 3 + 2];
      float dist = sqrtf(rx * rx + ry * ry + rz * rz);
      float cf = w / dist;
      sPE[tid * 3 + 0] = cf * rx;
      sPE[tid * 3 + 1] = cf * ry;
      sPE[tid * 3 + 2] = cf * rz;
    }
    bool head = (tid < nv) && (tid == 0 || sDst[tid] != sDst[tid - 1]);
    unsigned long long mask = __ballot(head);
    int r = __popcll(mask & ((1ull << tid) - 1ull));
    if (head) {
      unsigned long long rest = (tid == 63) ? 0ull : (mask >> (tid + 1));
      int end = rest ? (tid + __ffsll((long long)rest)) : nv;
      sRunS[r] = tid; sRunE[r] = end;
    }
    if (tid == 0) sNR = __popcll(mask);
  }
  __syncthreads();
  const int NR = sNR;

  // ---- pdelta: one thread per (run, component) ----
  if (tid < NR * 3) {
    int r = tid / 3, comp = tid - r * 3;
    int s = sRunS[r], e1 = sRunE[r];
    float sum = 0.f;
    for (int e = s; e < e1; ++e) sum += sPE[e * 3 + comp];
    atomicAdd(&pdelta[sDst[s] * 3 + comp], sum);
  }

  // ---- intra: (f, parity) threads over runs ----
  if (do_intra) {
    int f = tid & 127, par = tid >> 7;
    for (int r = par; r < NR; r += 2) {
      int s = sRunS[r], e1 = sRunE[r];
      float sum = 0.f;
      for (int e = s; e < e1; ++e) sum += b2f(sM[e * 136 + f]);
      atomicAdd(&intra[(size_t)sDst[s] * H + f], sum);
    }
  }
}

// ---------------- node kernel: same col-split structure ----------------

__launch_bounds__(256, 3)
__global__ void k_node(const unsigned short* __restrict__ xb,
                       const float* __restrict__ intra,
                       const float* __restrict__ invd,
                       const unsigned short* __restrict__ nW1t, const float* __restrict__ nb1,
                       const unsigned short* __restrict__ nW2t, const float* __restrict__ nb2,
                       const float* __restrict__ pos_in, const float* __restrict__ pdelta,
                       unsigned short* __restrict__ xb_out, float* __restrict__ pos_out,
                       int compute_x)
{
  __shared__ unsigned short sH[64 * 136];
  const int tid = threadIdx.x;
  const int n0 = blockIdx.x * 64;

  if (tid < 192) {
    int n = n0 + tid / 3, cc = tid % 3;
    if (n < N_NODES)
      pos_out[n * 3 + cc] = pos_in[n * 3 + cc] + pdelta[n * 3 + cc] * invd[n];
  }
  if (!compute_x) return;

  const int wv = tid >> 6, lane = tid & 63, quad = lane >> 4, ln15 = lane & 15;
  const int col = wv * 32 + ln15;

  int node_r[4]; float inv_r[4];
#pragma unroll
  for (int rt = 0; rt < 4; ++rt) {
    node_r[rt] = min(n0 + rt * 16 + ln15, N_NODES - 1);
    inv_r[rt] = invd[node_r[rt]];
  }

  f32x4 xacc[4][2];
#pragma unroll
  for (int rt = 0; rt < 4; ++rt)
#pragma unroll
    for (int ct = 0; ct < 2; ++ct) xacc[rt][ct] = (f32x4){0.f, 0.f, 0.f, 0.f};

  for (int h = 0; h < 2; ++h) {
    f32x4 acc[4][2];
#pragma unroll
    for (int rt = 0; rt < 4; ++rt)
#pragma unroll
      for (int ct = 0; ct < 2; ++ct) acc[rt][ct] = (f32x4){0.f, 0.f, 0.f, 0.f};

    // GEMM-A: concat(x, intra*invd) [64,256] @ nW1[:, h-half] — direct operands
    for (int c = 0; c < 4; ++c) {
      short8v af[4][2];
      if (c < 2) {
#pragma unroll
        for (int rt = 0; rt < 4; ++rt) {
          const unsigned short* p = xb + (size_t)node_r[rt] * H + c * 64 + quad * 8;
          af[rt][0] = *(const short8v*)p;
          af[rt][1] = *(const short8v*)(p + 32);
        }
      } else {
#pragma unroll
        for (int rt = 0; rt < 4; ++rt) {
          const float* p = intra + (size_t)node_r[rt] * H + (c - 2) * 64 + quad * 8;
          float iv = inv_r[rt];
          float4 q0 = *(const float4*)p;
          float4 q1 = *(const float4*)(p + 4);
          float4 q2 = *(const float4*)(p + 32);
          float4 q3 = *(const float4*)(p + 36);
          q0.x *= iv; q0.y *= iv; q0.z *= iv; q0.w *= iv;
          q1.x *= iv; q1.y *= iv; q1.z *= iv; q1.w *= iv;
          q2.x *= iv; q2.y *= iv; q2.z *= iv; q2.w *= iv;
          q3.x *= iv; q3.y *= iv; q3.z *= iv; q3.w *= iv;
          af[rt][0] = pack8(q0, q1);
          af[rt][1] = pack8(q2, q3);
        }
      }
      short8v bf[2][2];
#pragma unroll
      for (int ct = 0; ct < 2; ++ct) {
        const unsigned short* p = nW1t + (size_t)(h * 128 + col + ct * 16) * 256 + c * 64 + quad * 8;
        bf[ct][0] = *(const short8v*)p;
        bf[ct][1] = *(const short8v*)(p + 32);
      }
#pragma unroll
      for (int ks = 0; ks < 2; ++ks)
#pragma unroll
        for (int rt = 0; rt < 4; ++rt)
#pragma unroll
          for (int ct = 0; ct < 2; ++ct)
            acc[rt][ct] = MFMA16(af[rt][ks], bf[ct][ks], acc[rt][ct]);
    }
    // hidden half -> sH
    if (h == 1) __syncthreads();  // wait GEMM-B(h=0) reads before overwrite
    {
      float b0 = nb1[h * 128 + col], b1 = nb1[h * 128 + col + 16];
#pragma unroll
      for (int rt = 0; rt < 4; ++rt)
#pragma unroll
        for (int r = 0; r < 4; ++r) {
          int row = rt * 16 + quad * 4 + r;
          sH[row * 136 + col] = f2b(fmaxf(acc[rt][0][r] + b0, 0.f));
          sH[row * 136 + col + 16] = f2b(fmaxf(acc[rt][1][r] + b1, 0.f));
        }
    }
    __syncthreads();
    // GEMM-B partial: sH [64,128] @ nW2[h-half rows] into xacc
    for (int c2 = 0; c2 < 2; ++c2) {
      short8v af[4][2];
#pragma unroll
      for (int rt = 0; rt < 4; ++rt) {
        const unsigned short* p = &sH[(rt * 16 + ln15) * 136 + c2 * 64 + quad * 8];
        af[rt][0] = *(const short8v*)p;
        af[rt][1] = *(const short8v*)(p + 32);
      }
      short8v bf[2][2];
#pragma unroll
      for (int ct = 0; ct < 2; ++ct) {
        const unsigned short* p = nW2t + (size_t)(col + ct * 16) * 256 + h * 128 + c2 * 64 + quad * 8;
        bf[ct][0] = *(const short8v*)p;
        bf[ct][1] = *(const short8v*)(p + 32);
      }
#pragma unroll
      for (int ks = 0; ks < 2; ++ks)
#pragma unroll
        for (int rt = 0; rt < 4; ++rt)
#pragma unroll
          for (int ct = 0; ct < 2; ++ct)
            xacc[rt][ct] = MFMA16(af[rt][ks], bf[ct][ks], xacc[rt][ct]);
    }
  }
  // x_out = xacc + nb2 (bf16)
  {
    float b0 = nb2[col], b1 = nb2[col + 16];
#pragma unroll
    for (int rt = 0; rt < 4; ++rt)
#pragma unroll
      for (int r = 0; r < 4; ++r) {
        int row = n0 + rt * 16 + quad * 4 + r;
        if (row < N_NODES) {
          xb_out[(size_t)row * H + col] = f2b(xacc[rt][0][r] + b0);
          xb_out[(size_t)row * H + col + 16] = f2b(xacc[rt][1][r] + b1);
        }
      }
  }
}

extern "C" void kernel_launch(void* const* d_in, const int* in_sizes, int n_in,
                              void* d_out, int out_size, void* d_ws, size_t ws_size,
                              hipStream_t stream) {
  const float* x0    = (const float*)d_in[0];
  const int*   eidx  = (const int*)d_in[1];
  const float* eattr = (const float*)d_in[2];
  const float* pos0  = (const float*)d_in[3];
  const float* mW1 = (const float*)d_in[4];
  const float* mb1 = (const float*)d_in[5];
  const float* mW2 = (const float*)d_in[6];
  const float* mb2 = (const float*)d_in[7];
  const float* aW1 = (const float*)d_in[8];
  const float* ab1 = (const float*)d_in[9];
  const float* aW2 = (const float*)d_in[10];
  const float* ab2 = (const float*)d_in[11];
  const float* nW1 = (const float*)d_in[12];
  const float* nb1 = (const float*)d_in[13];
  const float* nW2 = (const float*)d_in[14];
  const float* nb2 = (const float*)d_in[15];
  const int* srcI = eidx;
  const int* dstI = eidx + N_EDGES;

  char* wsb = (char*)d_ws;
  int*   degC    = (int*)wsb;                     wsb += (size_t)N_NODES * 4;
  int*   cursor  = (int*)wsb;                     wsb += (size_t)N_NODES * 4;
  int*   chunkS  = (int*)wsb;                     wsb += 256 * 4;
  int*   sorted  = (int*)wsb;                     wsb += (size_t)N_EDGES * 4;
  float* invd    = (float*)wsb;                   wsb += (size_t)N_NODES * 4;
  float* pdelta  = (float*)wsb;                   wsb += (size_t)3 * N_NODES * 4;
  float* intra   = (float*)wsb;                   wsb += (size_t)N_NODES * H * 4;  // adjacent to pdelta (one memset)
  float* pos_a   = (float*)wsb;                   wsb += (size_t)3 * N_NODES * 4;
  float* pos_b   = (float*)wsb;                   wsb += (size_t)3 * N_NODES * 4;
  unsigned short* xb0  = (unsigned short*)wsb;    wsb += (size_t)N_NODES * H * 2;
  unsigned short* xb_a = (unsigned short*)wsb;    wsb += (size_t)N_NODES * H * 2;
  unsigned short* xb_b = (unsigned short*)wsb;    wsb += (size_t)N_NODES * H * 2;
  unsigned short* mW1t = (unsigned short*)wsb;    wsb += (size_t)NL * 128 * 384 * 2;
  unsigned short* mW2t = (unsigned short*)wsb;    wsb += (size_t)NL * 128 * 128 * 2;
  unsigned short* aW1t = (unsigned short*)wsb;    wsb += (size_t)NL * 256 * 128 * 2;
  unsigned short* nW1t = (unsigned short*)wsb;    wsb += (size_t)NL * 256 * 256 * 2;
  unsigned short* nW2t = (unsigned short*)wsb;    wsb += (size_t)NL * 128 * 256 * 2;

  // counting sort of edges by dst (every launch; ws is re-poisoned)
  hipMemsetAsync(degC, 0, N_NODES * sizeof(int), stream);
  k_deg_i<<<(N_EDGES + 255) / 256, 256, 0, stream>>>(dstI, degC);
  k_scan1<<<NCHUNK, SCAN_B, 0, stream>>>(degC, cursor, chunkS, invd);
  k_scan2<<<1, SCAN_B, 0, stream>>>(chunkS);
  k_scan3<<<NCHUNK, SCAN_B, 0, stream>>>(cursor, chunkS);
  k_scatter_sort<<<(N_EDGES + 255) / 256, 256, 0, stream>>>(dstI, cursor, sorted);

  // bf16 conversions
  {
    int n4 = N_NODES * H / 4;
    k_cvt_x<<<(n4 + 255) / 256, 256, 0, stream>>>(x0, xb0, n4);
    k_cvt_w<<<(589824 + 255) / 256, 256, 0, stream>>>(mW1, mW2, aW1, nW1, nW2,
                                                      mW1t, mW2t, aW1t, nW1t, nW2t);
  }

  const unsigned short* xc = xb0;
  const float* pc = pos0;
  float* pos_out_final = (float*)d_out;

  for (int l = 0; l < NL; ++l) {
    int last = (l == NL - 1);
    // pdelta + intra are adjacent: one memset
    hipMemsetAsync(pdelta, 0, (size_t)(3 * N_NODES + N_NODES * H) * sizeof(float), stream);

    k_edge<<<(N_EDGES + 63) / 64, 256, 0, stream>>>(
        xc, pc, eattr, srcI, dstI, sorted,
        mW1t + (size_t)l * 128 * 384, mb1 + (size_t)l * 128,
        mW2t + (size_t)l * 128 * 128, mb2 + (size_t)l * 128,
        aW1t + (size_t)l * 256 * 128, ab1 + (size_t)l * 256,
        aW2 + (size_t)l * 256, ab2 + l,
        intra, pdelta, last ? 0 : 1);

    float* pn = last ? pos_out_final : (l == 0 ? pos_a : pos_b);
    unsigned short* xn = (l == 0) ? xb_a : xb_b;
    k_node<<<(N_NODES + 63) / 64, 256, 0, stream>>>(
        xc, intra, invd,
        nW1t + (size_t)l * 256 * 256, nb1 + (size_t)l * 256,
        nW2t + (size_t)l * 128 * 256, nb2 + (size_t)l * 128,
        pc, pdelta, xn, pn, last ? 0 : 1);

    xc = xn;
    pc = pn;
  }
}